// Round 16
// baseline (201.487 us; speedup 1.0000x reference)
//
#include <hip/hip_runtime.h>
#include <cstdint>
#include <cstddef>

#define SEQ 2048
#define TILES 16
#define FRAG_SHORTS 12288                 // bf16 per 128-col tile (8 st * 3 frag * 64 lane * 8)
#define FRAG_BYTES  24576
#define PSTRIDE 36                        // shorts per row of wave-private transpose buf

typedef __attribute__((ext_vector_type(8))) short bf16x8;
typedef __attribute__((ext_vector_type(4))) float f32x4;
typedef __attribute__((ext_vector_type(4))) short short4v;
typedef __attribute__((ext_vector_type(2))) unsigned uint2v;

__device__ __forceinline__ short f2bf(float f) {
    union { float f; unsigned u; } a; a.f = f;
    unsigned r = a.u + 0x7fffu + ((a.u >> 16) & 1u);
    return (short)(r >> 16);
}
__device__ __forceinline__ float clip5(float v) { return fminf(fmaxf(v, -5.0f), 5.0f); }
__device__ __forceinline__ float bflo2f(unsigned u) { union { unsigned u; float f; } a; a.u = u << 16; return a.f; }
__device__ __forceinline__ float bfhi2f(unsigned u) { union { unsigned u; float f; } a; a.u = u & 0xffff0000u; return a.f; }

// ---- prepass: K/PK f32 -> clipped bf16 in MFMA A-fragment order ----
// ws layout: [bh(32)][tile(16)][st(8)][frag(3)][lane(64)][j(8)]
__global__ __launch_bounds__(256)
void prep_kernel(const float* __restrict__ Kp, const float* __restrict__ PKp,
                 short* __restrict__ wsK)
{
    int id = blockIdx.x * 256 + threadIdx.x;   // 65536 rows * 24 float4
    int q = id % 24;
    int row = id / 24;            // bh*2048 + col
    int bh = row >> 11;
    int col = row & 2047;
    int tile = col >> 7;
    int st = (col >> 4) & 7;
    int l15 = col & 15;
    float4 v;
    int f, dd;
    if (q < 16) {                 // keys: 16 float4 per row
        v = reinterpret_cast<const float4*>(Kp)[(size_t)row * 16 + q];
        f = q >> 3;
        dd = (q & 7) * 4;
    } else {                      // pos_key: 8 float4 per row
        v = reinterpret_cast<const float4*>(PKp)[(size_t)row * 8 + (q - 16)];
        f = 2;
        dd = (q - 16) * 4;
    }
    int ll = l15 | ((dd >> 3) << 4);
    int j = dd & 7;
    short4v s4;
    s4[0] = f2bf(clip5(v.x)); s4[1] = f2bf(clip5(v.y));
    s4[2] = f2bf(clip5(v.z)); s4[3] = f2bf(clip5(v.w));
    *reinterpret_cast<short4v*>(wsK + ((size_t)bh * TILES + tile) * FRAG_SHORTS
                                + (((st * 3 + f) * 64 + ll) << 3) + j) = s4;
}

// 2048 blocks x 512 thr (8 waves). Block: (bh, 32 q rows). Wave: rg=w&1 row
// half (16 rows), cs=w>>1 col quarter (32 cols per 128-col tile).
// Single compute sweep: P kept packed-bf16 in pk[64] VGPRs + row sums.
// Then a BARRIER-FREE store phase: per tile, transpose pk through a
// wave-private LDS buf and issue full-line contiguous CACHED stores.
// R16 vs R10 (single mechanism: who owns L2): staging global_load_lds gets
// aux=2 (NT, no L2 allocate -> served from L3 where wsK stays hot), and the
// output stores become CACHED (L2 write-combining streams at memset rates).
template<bool USEWS>
__global__ __launch_bounds__(512, 4)
void attn_map_kernel(const float* __restrict__ Kp, const float* __restrict__ Qp,
                     const float* __restrict__ PKp, const float* __restrict__ PQp,
                     const int* __restrict__ maskp, const short* __restrict__ wsK,
                     float* __restrict__ out)
{
    __shared__ short lds_k[2][FRAG_SHORTS];   // 48 KiB double buffer
    __shared__ float lds_madd[SEQ];           // (mask? -1e30:0) - SHIFT, 8 KiB
    __shared__ short lds_p[8][16 * PSTRIDE];  // 9 KiB wave-private transpose bufs
    __shared__ float sred[8][16];             // cross-wave row-sum partials
    __shared__ float lds_inv[8][16];          // per-wave copy of 1/rowsum

    // XCD-aware mapping: p%8 = XCD; 4 bh x 64 q-blocks per XCD.
    const int p = blockIdx.x;
    const int x = p & 7;
    const int slot = p >> 3;               // 0..255
    const int bh = x + 8 * (slot >> 6);    // {x, x+8, x+16, x+24}
    const int qb = slot & 63;              // 0..63

    const int tid = threadIdx.x;
    const int lane = tid & 63;
    const int w = tid >> 6;
    const int l15 = lane & 15;
    const int l4 = lane >> 4;
    const int rg = w & 1;
    const int cs = w >> 1;

    const int qrow = qb * 32 + rg * 16 + l15;

    const float* Qb  = Qp  + (size_t)bh * (SEQ * 64);
    const float* PQb = PQp + (size_t)bh * (SEQ * 32);
    const int*   mb  = maskp + (size_t)(bh >> 4) * SEQ;
    float* outb = out + (size_t)bh * SEQ * SEQ;

    const float QS  = 0.125f * 1.4426950408889634f;               // SCALE * log2(e)
    const float PQS = 0.17677669529663687f * 1.4426950408889634f; // REL_SCALE * log2(e)
    const float SHIFT = 28.853900817779268f;                      // 20 * log2(e)

    // ---- Q / PQ fragments (B operand): lane holds Q[qrow][l4*8 + j] ----
    bf16x8 qa[3];
    #pragma unroll
    for (int f = 0; f < 2; ++f) {
        const float* src = Qb + (size_t)qrow * 64 + f * 32 + l4 * 8;
        bf16x8 v;
        #pragma unroll
        for (int j = 0; j < 8; ++j) v[j] = f2bf(clip5(src[j]) * QS);
        qa[f] = v;
    }
    {
        const float* src = PQb + (size_t)qrow * 32 + l4 * 8;
        bf16x8 v;
        #pragma unroll
        for (int j = 0; j < 8; ++j) v[j] = f2bf(clip5(src[j]) * PQS);
        qa[2] = v;
    }

    // ---- mask -> LDS as additive floats, -SHIFT folded in ----
    #pragma unroll
    for (int i = 0; i < SEQ / 512; ++i) {
        int idx = i * 512 + tid;
        lds_madd[idx] = (mb[idx] ? -1e30f : 0.0f) - SHIFT;
    }

    const short* kf = USEWS ? (wsK + (size_t)bh * (TILES * FRAG_SHORTS)) : nullptr;

#define STAGE(T, B) do {                                                                   \
    if constexpr (USEWS) {                                                                 \
        const char* ksrc = (const char*)kf + (size_t)(T) * FRAG_BYTES;                     \
        _Pragma("unroll")                                                                  \
        for (int c = 0; c < 3; ++c) {                                                      \
            int off = w * 3072 + c * 1024;                                                 \
            __builtin_amdgcn_global_load_lds(                                              \
                (const __attribute__((address_space(1))) void*)(ksrc + off + lane * 16),   \
                (__attribute__((address_space(3))) void*)((char*)&lds_k[(B)][0] + off),    \
                16, 0, 2 /* NT: no L2 allocate; serve from L3 */);                         \
        }                                                                                  \
    } else {                                                                               \
        const int tile0 = (T) * 128;                                                       \
        _Pragma("unroll")                                                                  \
        for (int i = 0; i < 6; ++i) {                                                      \
            int e = i * 512 + tid;                                                         \
            int col = e / 24, dq = e - col * 24, d0 = dq * 4;                               \
            int colg = tile0 + col;                                                        \
            float4 v; int f, dd;                                                           \
            if (d0 < 64) {                                                                 \
                v = *reinterpret_cast<const float4*>(Kp + (size_t)bh * (SEQ * 64) + (size_t)colg * 64 + d0); \
                f = d0 >> 5; dd = d0 & 31;                                                 \
            } else {                                                                       \
                v = *reinterpret_cast<const float4*>(PKp + (size_t)bh * (SEQ * 32) + (size_t)colg * 32 + (d0 - 64)); \
                f = 2; dd = d0 - 64;                                                       \
            }                                                                              \
            int ll = (col & 15) | ((dd >> 3) << 4);                                        \
            int st2 = col >> 4, j = dd & 7;                                                \
            short4v s4;                                                                    \
            s4[0] = f2bf(clip5(v.x)); s4[1] = f2bf(clip5(v.y));                            \
            s4[2] = f2bf(clip5(v.z)); s4[3] = f2bf(clip5(v.w));                            \
            *reinterpret_cast<short4v*>(&lds_k[(B)][(((st2 * 3 + f) * 64 + ll) << 3) + j]) = s4; \
        }                                                                                  \
    }                                                                                      \
} while (0)

    unsigned pk[64];   // packed bf16 P: [tile(16)][sti(2)][pair(2)]
    float ssum = 0.0f;

    STAGE(0, 0);
    __syncthreads();

    // ---- single compute sweep (fully unrolled: pk indices must be static) ----
    #pragma unroll
    for (int t = 0; t < TILES; ++t) {
        if (t + 1 < TILES) STAGE(t + 1, (t + 1) & 1);
        const short* lk = &lds_k[t & 1][0];
        #pragma unroll
        for (int sti = 0; sti < 2; ++sti) {
            const int st = cs * 2 + sti;
            bf16x8 kb0 = *reinterpret_cast<const bf16x8*>(lk + ((st * 3 + 0) * 64 + lane) * 8);
            bf16x8 kb1 = *reinterpret_cast<const bf16x8*>(lk + ((st * 3 + 1) * 64 + lane) * 8);
            bf16x8 kb2 = *reinterpret_cast<const bf16x8*>(lk + ((st * 3 + 2) * 64 + lane) * 8);
            f32x4 madd4 = *reinterpret_cast<const f32x4*>(&lds_madd[t * 128 + st * 16 + l4 * 4]);
            f32x4 acc = {0.f, 0.f, 0.f, 0.f};
            acc = __builtin_amdgcn_mfma_f32_16x16x32_bf16(kb0, qa[0], acc, 0, 0, 0);
            acc = __builtin_amdgcn_mfma_f32_16x16x32_bf16(kb1, qa[1], acc, 0, 0, 0);
            acc = __builtin_amdgcn_mfma_f32_16x16x32_bf16(kb2, qa[2], acc, 0, 0, 0);
            float e0 = exp2f(acc[0] + madd4[0]);
            float e1 = exp2f(acc[1] + madd4[1]);
            float e2 = exp2f(acc[2] + madd4[2]);
            float e3 = exp2f(acc[3] + madd4[3]);
            ssum += (e0 + e1) + (e2 + e3);
            unsigned u0, u1;
            asm("v_cvt_pk_bf16_f32 %0, %1, %2" : "=v"(u0) : "v"(e0), "v"(e1));
            asm("v_cvt_pk_bf16_f32 %0, %1, %2" : "=v"(u1) : "v"(e2), "v"(e3));
            pk[t * 4 + sti * 2]     = u0;
            pk[t * 4 + sti * 2 + 1] = u1;
        }
        __syncthreads();
    }

    // ---- row-sum reduce: in-wave, then cross-wave (4 cs waves share rg) ----
    {
        float s = ssum;
        s += __shfl_xor(s, 16);
        s += __shfl_xor(s, 32);
        if (lane < 16) sred[w][l15] = s;
    }
    __syncthreads();
    {
        const float rs = (sred[rg][l15] + sred[rg + 2][l15])
                       + (sred[rg + 4][l15] + sred[rg + 6][l15]);
        if (lane < 16) lds_inv[w][l15] = 1.0f / rs;   // wave-private copy
    }

    // ---- store phase: NO barriers. Per tile: transpose via wave-private LDS,
    //      scale, full-line contiguous CACHED stores. ----
    short* pw = &lds_p[w][0];
    const int rowbase = qb * 32 + rg * 16;
    const int colbase = cs * 32;
    const int rl = lane >> 3;       // 0..7 (row within 8-row group)
    const int cg = lane & 7;        // 0..7 (16B column group)

    #pragma unroll
    for (int t = 0; t < TILES; ++t) {
        #pragma unroll
        for (int sti = 0; sti < 2; ++sti) {
            uint2v uu;
            uu[0] = pk[t * 4 + sti * 2];
            uu[1] = pk[t * 4 + sti * 2 + 1];
            *reinterpret_cast<uint2v*>(&pw[l15 * PSTRIDE + sti * 16 + l4 * 4]) = uu;
        }
        #pragma unroll
        for (int sblk = 0; sblk < 2; ++sblk) {
            const int row = sblk * 8 + rl;                  // local row 0..15
            uint2v uu = *reinterpret_cast<const uint2v*>(&pw[row * PSTRIDE + cg * 4]);
            const float invr = lds_inv[w][row];
            f32x4 pv = { bflo2f(uu[0]) * invr, bfhi2f(uu[0]) * invr,
                         bflo2f(uu[1]) * invr, bfhi2f(uu[1]) * invr };
            *reinterpret_cast<f32x4*>(outb + (size_t)(rowbase + row) * SEQ
                                      + t * 128 + colbase + cg * 4) = pv;
        }
    }
#undef STAGE
}

extern "C" void kernel_launch(void* const* d_in, const int* in_sizes, int n_in,
                              void* d_out, int out_size, void* d_ws, size_t ws_size,
                              hipStream_t stream) {
    const float* keys      = (const float*)d_in[0];
    const float* queries   = (const float*)d_in[1];
    const float* pos_key   = (const float*)d_in[2];
    const float* pos_query = (const float*)d_in[3];
    const int*   mask      = (const int*)d_in[4];
    float* outp = (float*)d_out;

    const size_t need = (size_t)32 * TILES * FRAG_SHORTS * sizeof(short); // 12.58 MB
    if (ws_size >= need) {
        short* wsK = (short*)d_ws;
        prep_kernel<<<dim3(6144), dim3(256), 0, stream>>>(keys, pos_key, wsK);
        attn_map_kernel<true><<<dim3(2048), dim3(512), 0, stream>>>(
            keys, queries, pos_key, pos_query, mask, wsK, outp);
    } else {
        attn_map_kernel<false><<<dim3(2048), dim3(512), 0, stream>>>(
            keys, queries, pos_key, pos_query, mask, nullptr, outp);
    }
}

// Round 17
// 148.987 us; speedup vs baseline: 1.3524x; 1.3524x over previous
//
#include <hip/hip_runtime.h>
#include <cstdint>
#include <cstddef>

#define SEQ 2048
#define TILES 16
#define FRAG_SHORTS 12288                 // bf16 per 128-col tile (8 st * 3 frag * 64 lane * 8)
#define FRAG_BYTES  24576
#define PSTRIDE 36                        // shorts per row of wave-private transpose buf

typedef __attribute__((ext_vector_type(8))) short bf16x8;
typedef __attribute__((ext_vector_type(4))) float f32x4;
typedef __attribute__((ext_vector_type(4))) short short4v;
typedef __attribute__((ext_vector_type(2))) unsigned uint2v;

__device__ __forceinline__ short f2bf(float f) {
    union { float f; unsigned u; } a; a.f = f;
    unsigned r = a.u + 0x7fffu + ((a.u >> 16) & 1u);
    return (short)(r >> 16);
}
__device__ __forceinline__ float clip5(float v) { return fminf(fmaxf(v, -5.0f), 5.0f); }
__device__ __forceinline__ float bflo2f(unsigned u) { union { unsigned u; float f; } a; a.u = u << 16; return a.f; }
__device__ __forceinline__ float bfhi2f(unsigned u) { union { unsigned u; float f; } a; a.u = u & 0xffff0000u; return a.f; }

// ---- prepass: K/PK f32 -> clipped bf16 in MFMA A-fragment order ----
// ws layout: [bh(32)][tile(16)][st(8)][frag(3)][lane(64)][j(8)]
__global__ __launch_bounds__(256)
void prep_kernel(const float* __restrict__ Kp, const float* __restrict__ PKp,
                 short* __restrict__ wsK)
{
    int id = blockIdx.x * 256 + threadIdx.x;   // 65536 rows * 24 float4
    int q = id % 24;
    int row = id / 24;            // bh*2048 + col
    int bh = row >> 11;
    int col = row & 2047;
    int tile = col >> 7;
    int st = (col >> 4) & 7;
    int l15 = col & 15;
    float4 v;
    int f, dd;
    if (q < 16) {                 // keys: 16 float4 per row
        v = reinterpret_cast<const float4*>(Kp)[(size_t)row * 16 + q];
        f = q >> 3;
        dd = (q & 7) * 4;
    } else {                      // pos_key: 8 float4 per row
        v = reinterpret_cast<const float4*>(PKp)[(size_t)row * 8 + (q - 16)];
        f = 2;
        dd = (q - 16) * 4;
    }
    int ll = l15 | ((dd >> 3) << 4);
    int j = dd & 7;
    short4v s4;
    s4[0] = f2bf(clip5(v.x)); s4[1] = f2bf(clip5(v.y));
    s4[2] = f2bf(clip5(v.z)); s4[3] = f2bf(clip5(v.w));
    *reinterpret_cast<short4v*>(wsK + ((size_t)bh * TILES + tile) * FRAG_SHORTS
                                + (((st * 3 + f) * 64 + ll) << 3) + j) = s4;
}

// 2048 blocks x 512 thr (8 waves). Block: (bh, 32 q rows). Wave: rg=w&1 row
// half (16 rows), cs=w>>1 col quarter (32 cols per 128-col tile).
// Single compute sweep: P kept packed-bf16 in pk[64] VGPRs + row sums.
// Then a BARRIER-FREE store phase: per tile, transpose pk through a
// wave-private LDS buf and issue full-line contiguous nontemporal stores.
// (nt stores bypass L2, keeping the wsK staging panels L2-resident — the
// best measured write-path configuration: R10=149.7us vs cached variants
// 175-201us.)
template<bool USEWS>
__global__ __launch_bounds__(512, 4)
void attn_map_kernel(const float* __restrict__ Kp, const float* __restrict__ Qp,
                     const float* __restrict__ PKp, const float* __restrict__ PQp,
                     const int* __restrict__ maskp, const short* __restrict__ wsK,
                     float* __restrict__ out)
{
    __shared__ short lds_k[2][FRAG_SHORTS];   // 48 KiB double buffer
    __shared__ float lds_madd[SEQ];           // (mask? -1e30:0) - SHIFT, 8 KiB
    __shared__ short lds_p[8][16 * PSTRIDE];  // 9 KiB wave-private transpose bufs
    __shared__ float sred[8][16];             // cross-wave row-sum partials
    __shared__ float lds_inv[8][16];          // per-wave copy of 1/rowsum

    // XCD-aware mapping: p%8 = XCD; 4 bh x 64 q-blocks per XCD.
    const int p = blockIdx.x;
    const int x = p & 7;
    const int slot = p >> 3;               // 0..255
    const int bh = x + 8 * (slot >> 6);    // {x, x+8, x+16, x+24}
    const int qb = slot & 63;              // 0..63

    const int tid = threadIdx.x;
    const int lane = tid & 63;
    const int w = tid >> 6;
    const int l15 = lane & 15;
    const int l4 = lane >> 4;
    const int rg = w & 1;
    const int cs = w >> 1;

    const int qrow = qb * 32 + rg * 16 + l15;

    const float* Qb  = Qp  + (size_t)bh * (SEQ * 64);
    const float* PQb = PQp + (size_t)bh * (SEQ * 32);
    const int*   mb  = maskp + (size_t)(bh >> 4) * SEQ;
    float* outb = out + (size_t)bh * SEQ * SEQ;

    const float QS  = 0.125f * 1.4426950408889634f;               // SCALE * log2(e)
    const float PQS = 0.17677669529663687f * 1.4426950408889634f; // REL_SCALE * log2(e)
    const float SHIFT = 28.853900817779268f;                      // 20 * log2(e)

    // ---- Q / PQ fragments (B operand): lane holds Q[qrow][l4*8 + j] ----
    bf16x8 qa[3];
    #pragma unroll
    for (int f = 0; f < 2; ++f) {
        const float* src = Qb + (size_t)qrow * 64 + f * 32 + l4 * 8;
        bf16x8 v;
        #pragma unroll
        for (int j = 0; j < 8; ++j) v[j] = f2bf(clip5(src[j]) * QS);
        qa[f] = v;
    }
    {
        const float* src = PQb + (size_t)qrow * 32 + l4 * 8;
        bf16x8 v;
        #pragma unroll
        for (int j = 0; j < 8; ++j) v[j] = f2bf(clip5(src[j]) * PQS);
        qa[2] = v;
    }

    // ---- mask -> LDS as additive floats, -SHIFT folded in ----
    #pragma unroll
    for (int i = 0; i < SEQ / 512; ++i) {
        int idx = i * 512 + tid;
        lds_madd[idx] = (mb[idx] ? -1e30f : 0.0f) - SHIFT;
    }

    const short* kf = USEWS ? (wsK + (size_t)bh * (TILES * FRAG_SHORTS)) : nullptr;

#define STAGE(T, B) do {                                                                   \
    if constexpr (USEWS) {                                                                 \
        const char* ksrc = (const char*)kf + (size_t)(T) * FRAG_BYTES;                     \
        _Pragma("unroll")                                                                  \
        for (int c = 0; c < 3; ++c) {                                                      \
            int off = w * 3072 + c * 1024;                                                 \
            __builtin_amdgcn_global_load_lds(                                              \
                (const __attribute__((address_space(1))) void*)(ksrc + off + lane * 16),   \
                (__attribute__((address_space(3))) void*)((char*)&lds_k[(B)][0] + off),    \
                16, 0, 0);                                                                 \
        }                                                                                  \
    } else {                                                                               \
        const int tile0 = (T) * 128;                                                       \
        _Pragma("unroll")                                                                  \
        for (int i = 0; i < 6; ++i) {                                                      \
            int e = i * 512 + tid;                                                         \
            int col = e / 24, dq = e - col * 24, d0 = dq * 4;                               \
            int colg = tile0 + col;                                                        \
            float4 v; int f, dd;                                                           \
            if (d0 < 64) {                                                                 \
                v = *reinterpret_cast<const float4*>(Kp + (size_t)bh * (SEQ * 64) + (size_t)colg * 64 + d0); \
                f = d0 >> 5; dd = d0 & 31;                                                 \
            } else {                                                                       \
                v = *reinterpret_cast<const float4*>(PKp + (size_t)bh * (SEQ * 32) + (size_t)colg * 32 + (d0 - 64)); \
                f = 2; dd = d0 - 64;                                                       \
            }                                                                              \
            int ll = (col & 15) | ((dd >> 3) << 4);                                        \
            int st2 = col >> 4, j = dd & 7;                                                \
            short4v s4;                                                                    \
            s4[0] = f2bf(clip5(v.x)); s4[1] = f2bf(clip5(v.y));                            \
            s4[2] = f2bf(clip5(v.z)); s4[3] = f2bf(clip5(v.w));                            \
            *reinterpret_cast<short4v*>(&lds_k[(B)][(((st2 * 3 + f) * 64 + ll) << 3) + j]) = s4; \
        }                                                                                  \
    }                                                                                      \
} while (0)

    unsigned pk[64];   // packed bf16 P: [tile(16)][sti(2)][pair(2)]
    float ssum = 0.0f;

    STAGE(0, 0);
    __syncthreads();

    // ---- single compute sweep (fully unrolled: pk indices must be static) ----
    #pragma unroll
    for (int t = 0; t < TILES; ++t) {
        if (t + 1 < TILES) STAGE(t + 1, (t + 1) & 1);
        const short* lk = &lds_k[t & 1][0];
        #pragma unroll
        for (int sti = 0; sti < 2; ++sti) {
            const int st = cs * 2 + sti;
            bf16x8 kb0 = *reinterpret_cast<const bf16x8*>(lk + ((st * 3 + 0) * 64 + lane) * 8);
            bf16x8 kb1 = *reinterpret_cast<const bf16x8*>(lk + ((st * 3 + 1) * 64 + lane) * 8);
            bf16x8 kb2 = *reinterpret_cast<const bf16x8*>(lk + ((st * 3 + 2) * 64 + lane) * 8);
            f32x4 madd4 = *reinterpret_cast<const f32x4*>(&lds_madd[t * 128 + st * 16 + l4 * 4]);
            f32x4 acc = {0.f, 0.f, 0.f, 0.f};
            acc = __builtin_amdgcn_mfma_f32_16x16x32_bf16(kb0, qa[0], acc, 0, 0, 0);
            acc = __builtin_amdgcn_mfma_f32_16x16x32_bf16(kb1, qa[1], acc, 0, 0, 0);
            acc = __builtin_amdgcn_mfma_f32_16x16x32_bf16(kb2, qa[2], acc, 0, 0, 0);
            float e0 = exp2f(acc[0] + madd4[0]);
            float e1 = exp2f(acc[1] + madd4[1]);
            float e2 = exp2f(acc[2] + madd4[2]);
            float e3 = exp2f(acc[3] + madd4[3]);
            ssum += (e0 + e1) + (e2 + e3);
            unsigned u0, u1;
            asm("v_cvt_pk_bf16_f32 %0, %1, %2" : "=v"(u0) : "v"(e0), "v"(e1));
            asm("v_cvt_pk_bf16_f32 %0, %1, %2" : "=v"(u1) : "v"(e2), "v"(e3));
            pk[t * 4 + sti * 2]     = u0;
            pk[t * 4 + sti * 2 + 1] = u1;
        }
        __syncthreads();
    }

    // ---- row-sum reduce: in-wave, then cross-wave (4 cs waves share rg) ----
    {
        float s = ssum;
        s += __shfl_xor(s, 16);
        s += __shfl_xor(s, 32);
        if (lane < 16) sred[w][l15] = s;
    }
    __syncthreads();
    {
        const float rs = (sred[rg][l15] + sred[rg + 2][l15])
                       + (sred[rg + 4][l15] + sred[rg + 6][l15]);
        if (lane < 16) lds_inv[w][l15] = 1.0f / rs;   // wave-private copy
    }

    // ---- store phase: NO barriers. Per tile: transpose via wave-private LDS,
    //      scale, full-line contiguous nontemporal stores. ----
    short* pw = &lds_p[w][0];
    const int rowbase = qb * 32 + rg * 16;
    const int colbase = cs * 32;
    const int rl = lane >> 3;       // 0..7 (row within 8-row group)
    const int cg = lane & 7;        // 0..7 (16B column group)

    #pragma unroll
    for (int t = 0; t < TILES; ++t) {
        #pragma unroll
        for (int sti = 0; sti < 2; ++sti) {
            uint2v uu;
            uu[0] = pk[t * 4 + sti * 2];
            uu[1] = pk[t * 4 + sti * 2 + 1];
            *reinterpret_cast<uint2v*>(&pw[l15 * PSTRIDE + sti * 16 + l4 * 4]) = uu;
        }
        #pragma unroll
        for (int sblk = 0; sblk < 2; ++sblk) {
            const int row = sblk * 8 + rl;                  // local row 0..15
            uint2v uu = *reinterpret_cast<const uint2v*>(&pw[row * PSTRIDE + cg * 4]);
            const float invr = lds_inv[w][row];
            f32x4 pv = { bflo2f(uu[0]) * invr, bfhi2f(uu[0]) * invr,
                         bflo2f(uu[1]) * invr, bfhi2f(uu[1]) * invr };
            __builtin_nontemporal_store(pv,
                reinterpret_cast<f32x4*>(outb + (size_t)(rowbase + row) * SEQ
                                         + t * 128 + colbase + cg * 4));
        }
    }
#undef STAGE
}

extern "C" void kernel_launch(void* const* d_in, const int* in_sizes, int n_in,
                              void* d_out, int out_size, void* d_ws, size_t ws_size,
                              hipStream_t stream) {
    const float* keys      = (const float*)d_in[0];
    const float* queries   = (const float*)d_in[1];
    const float* pos_key   = (const float*)d_in[2];
    const float* pos_query = (const float*)d_in[3];
    const int*   mask      = (const int*)d_in[4];
    float* outp = (float*)d_out;

    const size_t need = (size_t)32 * TILES * FRAG_SHORTS * sizeof(short); // 12.58 MB
    if (ws_size >= need) {
        short* wsK = (short*)d_ws;
        prep_kernel<<<dim3(6144), dim3(256), 0, stream>>>(keys, pos_key, wsK);
        attn_map_kernel<true><<<dim3(2048), dim3(512), 0, stream>>>(
            keys, queries, pos_key, pos_query, mask, wsK, outp);
    } else {
        attn_map_kernel<false><<<dim3(2048), dim3(512), 0, stream>>>(
            keys, queries, pos_key, pos_query, mask, nullptr, outp);
    }
}